// Round 6
// baseline (347.312 us; speedup 1.0000x reference)
//
#include <hip/hip_runtime.h>
#include <hip/hip_cooperative_groups.h>
#include <cstdint>

namespace cg = cooperative_groups;

typedef unsigned short u16;
typedef unsigned int   u32;

#define DIM     128
#define TPITCH  136          // LDS W row pitch in bf16 (bank-spread)
#define BSH     9            // nodes per fine bucket = 512
#define BSIZE   512
#define NBK_MAX 256          // supports n <= 131072
#define CHUNK   8192         // edges per L1 sort block

__device__ __forceinline__ u16 f2bf(float x) {   // fp32 -> bf16 RTNE
    u32 u = __float_as_uint(x);
    u32 r = u + 0x7FFFu + ((u >> 16) & 1u);
    return (u16)(r >> 16);
}

typedef __attribute__((ext_vector_type(8))) short bfrag;
typedef __attribute__((ext_vector_type(4))) float f32x4;

// ---------------------------------------------------------------------------
// K1: T(bf16) = A @ W^T with mfma_f32_16x16x32_bf16 (A, W cast in-flight).
// Wave: 16 rows x 128 cols (8 col-tiles, 4 k-steps, 32 MFMA). 64 rows/block.
// ---------------------------------------------------------------------------
__global__ __launch_bounds__(256) void k_transform(
    const float* __restrict__ A, const float* __restrict__ W,
    u16* __restrict__ Tb, int n)
{
    __shared__ u16 Wb[DIM * TPITCH];

    {   // stage W as bf16: Wb[j][k]
        const int j  = threadIdx.x >> 1;
        const int k0 = (threadIdx.x & 1) << 6;
        const float* wr = W + j * DIM + k0;
        u16* wo = Wb + j * TPITCH + k0;
#pragma unroll
        for (int k = 0; k < 64; k += 4) {
            float4 v = *(const float4*)(wr + k);
            ushort4 h;
            h.x = f2bf(v.x); h.y = f2bf(v.y); h.z = f2bf(v.z); h.w = f2bf(v.w);
            *(ushort4*)(wo + k) = h;
        }
    }
    __syncthreads();

    const int wave = threadIdx.x >> 6;
    const int lane = threadIdx.x & 63;
    const int quad = lane >> 4;
    const int l16  = lane & 15;

    const int r0 = ((blockIdx.x << 2) + wave) << 4;   // 16 rows per wave
    if (r0 >= n) return;                              // wave-uniform

    const int ar = min(r0 + l16, n - 1);
    const float* arow = A + (size_t)ar * DIM;

    f32x4 acc[8];
#pragma unroll
    for (int c = 0; c < 8; ++c) acc[c] = (f32x4)(0.f);

#pragma unroll
    for (int s = 0; s < 4; ++s) {
        const int koff = (s << 5) + (quad << 3);
        const float4 f0 = *(const float4*)(arow + koff);
        const float4 f1 = *(const float4*)(arow + koff + 4);
        bfrag a;
        a[0] = (short)f2bf(f0.x); a[1] = (short)f2bf(f0.y);
        a[2] = (short)f2bf(f0.z); a[3] = (short)f2bf(f0.w);
        a[4] = (short)f2bf(f1.x); a[5] = (short)f2bf(f1.y);
        a[6] = (short)f2bf(f1.z); a[7] = (short)f2bf(f1.w);
#pragma unroll
        for (int c = 0; c < 8; ++c) {
            const int nn = (c << 4) + l16;
            const bfrag b = *(const bfrag*)(Wb + nn * TPITCH + koff);
            acc[c] = __builtin_amdgcn_mfma_f32_16x16x32_bf16(a, b, acc[c], 0, 0, 0);
        }
    }

#pragma unroll
    for (int r = 0; r < 4; ++r) {
        const int row = r0 + (quad << 2) + r;
        if (row < n) {
            u16* orow = Tb + (size_t)row * DIM + l16;
#pragma unroll
            for (int c = 0; c < 8; ++c)
                orow[c << 4] = f2bf(acc[c][r]);
        }
    }
}

// ---------------------------------------------------------------------------
// K2 (cooperative, grid = max(NBK, nCntBlk) blocks, all co-resident):
//   A: per-chunk LDS histogram -> cnt[b][k]      (block-exclusive row write)
//   B: every block reduces cnt (coalesced cols) -> bucketStart + own lpos,
//      all kept in LDS (no global scan arrays)
//   C: scatter edges into per-(bucket,block) block-exclusive runs (es1)
//   D: fine sort within bucket b -> exact CSR off[] + es2
// ---------------------------------------------------------------------------
__global__ __launch_bounds__(256) void k_sort(
    const int* __restrict__ src, const int* __restrict__ dst,
    const float* __restrict__ w, int* __restrict__ cnt,
    int2* __restrict__ es1, int2* __restrict__ es2, int* __restrict__ off,
    int n, int E, int NBK, int nCntBlk)
{
    cg::grid_group grid = cg::this_grid();

    __shared__ int lpos[NBK_MAX];
    __shared__ int bstart[NBK_MAX + 1];
    __shared__ int sums[256];
    __shared__ int cfine[BSIZE];
    __shared__ int curf[BSIZE];

    const int b = blockIdx.x;
    const int t = threadIdx.x;

    // ---- Phase A: count ----
    if (b < nCntBlk) {
        for (int i = t; i < NBK; i += 256) lpos[i] = 0;
        __syncthreads();
        const int base = b * CHUNK;
        const int end  = min(base + CHUNK, E);
        for (int i = base + t; i < end; i += 256)
            atomicAdd(&lpos[dst[i] >> BSH], 1);
        __syncthreads();
        for (int k = t; k < NBK; k += 256)
            cnt[b * NBK + k] = lpos[k];
    }
    grid.sync();

    // ---- Phase B: scan (redundant per block; coalesced column reads) ----
    {
        int tot = 0, partial = 0;
        if (t < NBK) {
            const int bcap = min(b, nCntBlk);
#pragma unroll 4
            for (int q = 0; q < bcap; ++q) {
                const int c = cnt[q * NBK + t];
                partial += c; tot += c;
            }
#pragma unroll 4
            for (int q = bcap; q < nCntBlk; ++q)
                tot += cnt[q * NBK + t];
        }
        sums[t] = tot; __syncthreads();
        for (int d = 1; d < 256; d <<= 1) {
            int v = (t >= d) ? sums[t - d] : 0;
            __syncthreads();
            sums[t] += v;
            __syncthreads();
        }
        if (t < NBK) bstart[t] = sums[t] - tot;
        if (t == 0) bstart[NBK] = E;
        __syncthreads();
        if (b < nCntBlk && t < NBK) lpos[t] = bstart[t] + partial;
        __syncthreads();
    }

    // ---- Phase C: scatter into block-exclusive runs ----
    if (b < nCntBlk) {
        const int base = b * CHUNK;
        const int end  = min(base + CHUNK, E);
        for (int i = base + t; i < end; i += 256) {
            const int d = dst[i];
            const int p = atomicAdd(&lpos[d >> BSH], 1);
            es1[p] = make_int2(src[i] | ((d & (BSIZE - 1)) << 20),
                               __float_as_int(w[i]));
        }
    }
    grid.sync();

    // ---- Phase D: fine sort, block b = bucket b ----
    if (b < NBK) {
        const int s = bstart[b], e = bstart[b + 1];
        cfine[2 * t] = 0; cfine[2 * t + 1] = 0;
        __syncthreads();
        for (int i = s + t; i < e; i += 256)
            atomicAdd(&cfine[es1[i].x >> 20], 1);
        __syncthreads();

        const int c0 = cfine[2 * t], c1 = cfine[2 * t + 1];
        const int ts = c0 + c1;
        sums[t] = ts; __syncthreads();
        for (int d = 1; d < 256; d <<= 1) {
            int v = (t >= d) ? sums[t - d] : 0;
            __syncthreads();
            sums[t] += v;
            __syncthreads();
        }
        const int pre = sums[t] - ts;
        const int p0 = s + pre, p1 = p0 + c0;
        curf[2 * t] = p0; curf[2 * t + 1] = p1;

        const int v0 = (b << BSH) + 2 * t, v1 = v0 + 1;
        if (v0 < n) off[v0] = p0;
        if (v1 < n) off[v1] = p1;
        if (b == NBK - 1 && t == 0) off[n] = E;
        __syncthreads();

        for (int i = s + t; i < e; i += 256) {
            const int2 ev = es1[i];
            const int p = atomicAdd(&curf[ev.x >> 20], 1);
            es2[p] = make_int2(ev.x & 0xFFFFF, ev.y);
        }
    }
}

// ---------------------------------------------------------------------------
// K3: aggregate. One wave per node; lane holds 1 dword (2 bf16); unroll-4.
// ---------------------------------------------------------------------------
__global__ __launch_bounds__(256) void gnn_aggregate(
    const u16* __restrict__ Tb, const int* __restrict__ off,
    const int2* __restrict__ es, float* __restrict__ out, int n)
{
    const int v = blockIdx.x * 4 + (threadIdx.x >> 6);
    if (v >= n) return;
    const int lane = threadIdx.x & 63;
    const u32* Tw = (const u32*)Tb;

    const int b = off[v], e = off[v + 1];
    float ax = 0.f, ay = 0.f;

    int i = b;
    for (; i + 3 < e; i += 4) {
        const int2 e0 = es[i], e1 = es[i + 1], e2 = es[i + 2], e3 = es[i + 3];
        const u32 t0 = Tw[(size_t)e0.x * 64 + lane];
        const u32 t1 = Tw[(size_t)e1.x * 64 + lane];
        const u32 t2 = Tw[(size_t)e2.x * 64 + lane];
        const u32 t3 = Tw[(size_t)e3.x * 64 + lane];
        const float w0 = __int_as_float(e0.y), w1 = __int_as_float(e1.y);
        const float w2 = __int_as_float(e2.y), w3 = __int_as_float(e3.y);
        ax += w0 * __uint_as_float(t0 << 16);
        ay += w0 * __uint_as_float(t0 & 0xFFFF0000u);
        ax += w1 * __uint_as_float(t1 << 16);
        ay += w1 * __uint_as_float(t1 & 0xFFFF0000u);
        ax += w2 * __uint_as_float(t2 << 16);
        ay += w2 * __uint_as_float(t2 & 0xFFFF0000u);
        ax += w3 * __uint_as_float(t3 << 16);
        ay += w3 * __uint_as_float(t3 & 0xFFFF0000u);
    }
    for (; i < e; ++i) {
        const int2 ev = es[i];
        const u32 t = Tw[(size_t)ev.x * 64 + lane];
        const float w = __int_as_float(ev.y);
        ax += w * __uint_as_float(t << 16);
        ay += w * __uint_as_float(t & 0xFFFF0000u);
    }

    *(float2*)(out + (size_t)v * DIM + 2 * lane) = make_float2(ax, ay);
}

// ---------------------------------------------------------------------------
extern "C" void kernel_launch(void* const* d_in, const int* in_sizes, int n_in,
                              void* d_out, int out_size, void* d_ws, size_t ws_size,
                              hipStream_t stream)
{
    const float* node_emb = (const float*)d_in[0];
    const float* ew       = (const float*)d_in[1];
    const int*   srcp     = (const int*)d_in[2];
    const int*   dstp     = (const int*)d_in[3];
    const float* W        = (const float*)d_in[4];
    float* out = (float*)d_out;

    int n = in_sizes[0] / DIM;                  // 100000
    int E = in_sizes[1];                        // 1600000
    int NBK = (n + BSIZE - 1) >> BSH;           // 196 fine buckets
    int nCntBlk = (E + CHUNK - 1) / CHUNK;      // 196 chunks
    const int M = NBK * nCntBlk;

    // workspace layout (256B-aligned chunks)
    char* ws = (char*)d_ws;
    size_t o = 0;
    u16* Tb = (u16*)(ws + o);  o += (((size_t)n * DIM * sizeof(u16)) + 255) & ~255ULL;
    int* cnt = (int*)(ws + o); o += (((size_t)M * sizeof(int)) + 255) & ~255ULL;
    int* off = (int*)(ws + o); o += (((size_t)(n + 1) * sizeof(int)) + 255) & ~255ULL;
    int2* es1 = (int2*)(ws + o); o += (((size_t)E * sizeof(int2)) + 255) & ~255ULL;
    int2* es2 = (int2*)(ws + o);

    // K1: MFMA transform
    const int ntiles = (n + 63) >> 6;
    k_transform<<<ntiles, 256, 0, stream>>>(node_emb, W, Tb, n);

    // K2: fused CSR build (cooperative: count -> scan -> scatter -> fine)
    {
        int NBLK = (NBK > nCntBlk) ? NBK : nCntBlk;
        void* args[] = {
            (void*)&srcp, (void*)&dstp, (void*)&ew, (void*)&cnt,
            (void*)&es1, (void*)&es2, (void*)&off,
            (void*)&n, (void*)&E, (void*)&NBK, (void*)&nCntBlk
        };
        hipLaunchCooperativeKernel((const void*)k_sort, dim3(NBLK), dim3(256),
                                   args, 0, stream);
    }

    // K3: aggregate (one wave per node)
    gnn_aggregate<<<(n + 3) / 4, 256, 0, stream>>>(Tb, off, es2, out, n);
}

// Round 8
// 296.743 us; speedup vs baseline: 1.1704x; 1.1704x over previous
//
#include <hip/hip_runtime.h>
#include <cstdint>

typedef unsigned short u16;
typedef unsigned int   u32;

#define DIM     128
#define TPITCH  136          // LDS W row pitch in bf16 (bank-spread)
#define BSH     8            // nodes per fine bucket = 256
#define BSIZE   256
#define NBK_MAX 512          // supports n <= 131072
#define CHUNK   2048         // edges per count/scatter block

__device__ __forceinline__ u16 f2bf(float x) {   // fp32 -> bf16 RTNE
    u32 u = __float_as_uint(x);
    u32 r = u + 0x7FFFu + ((u >> 16) & 1u);
    return (u16)(r >> 16);
}

typedef __attribute__((ext_vector_type(8))) short bfrag;
typedef __attribute__((ext_vector_type(4))) float f32x4;

// ---------------------------------------------------------------------------
// K1 (fat): blocks [0, nCnt) histogram their edge chunk into global tot[];
// blocks [nCnt, nCnt+nTile) compute T(bf16) = A @ W^T with MFMA.
// Transform: 256 rows/block (4 waves x 4 tiles x 16 rows), W staged once.
// ---------------------------------------------------------------------------
__global__ __launch_bounds__(256) void k_count_transform(
    const float* __restrict__ A, const float* __restrict__ W,
    u16* __restrict__ Tb,
    const int* __restrict__ dst, int* __restrict__ tot,
    int n, int E, int nCnt, int NBK)
{
    __shared__ u16 Wb[DIM * TPITCH];   // 34816 B; count blocks reuse as hist

    if (blockIdx.x < nCnt) {
        int* hist = (int*)Wb;
        for (int i = threadIdx.x; i < NBK; i += 256) hist[i] = 0;
        __syncthreads();
        const int base = blockIdx.x * CHUNK;
        const int end  = min(base + CHUNK, E);
        for (int i = base + threadIdx.x; i < end; i += 256)
            atomicAdd(&hist[dst[i] >> BSH], 1);
        __syncthreads();
        for (int b = threadIdx.x; b < NBK; b += 256) {
            const int c = hist[b];
            if (c) atomicAdd(&tot[b], c);
        }
        return;
    }

    // stage W as bf16: Wb[j][k]
    {
        const int j  = threadIdx.x >> 1;
        const int k0 = (threadIdx.x & 1) << 6;
        const float* wr = W + j * DIM + k0;
        u16* wo = Wb + j * TPITCH + k0;
#pragma unroll
        for (int k = 0; k < 64; k += 4) {
            float4 v = *(const float4*)(wr + k);
            ushort4 h;
            h.x = f2bf(v.x); h.y = f2bf(v.y); h.z = f2bf(v.z); h.w = f2bf(v.w);
            *(ushort4*)(wo + k) = h;
        }
    }
    __syncthreads();

    const int wave = threadIdx.x >> 6;
    const int lane = threadIdx.x & 63;
    const int quad = lane >> 4;
    const int l16  = lane & 15;
    const int rbase = (blockIdx.x - nCnt) << 8;       // 256 rows per block

#pragma unroll 1
    for (int tile = 0; tile < 4; ++tile) {
        const int r0 = rbase + (tile << 6) + (wave << 4);   // 16 rows per wave
        if (r0 >= n) break;                                 // no barriers below

        const int ar = min(r0 + l16, n - 1);
        const float* arow = A + (size_t)ar * DIM;

        f32x4 acc[8];
#pragma unroll
        for (int c = 0; c < 8; ++c) acc[c] = (f32x4)(0.f);

#pragma unroll
        for (int s = 0; s < 4; ++s) {
            const int koff = (s << 5) + (quad << 3);
            const float4 f0 = *(const float4*)(arow + koff);
            const float4 f1 = *(const float4*)(arow + koff + 4);
            bfrag a;
            a[0] = (short)f2bf(f0.x); a[1] = (short)f2bf(f0.y);
            a[2] = (short)f2bf(f0.z); a[3] = (short)f2bf(f0.w);
            a[4] = (short)f2bf(f1.x); a[5] = (short)f2bf(f1.y);
            a[6] = (short)f2bf(f1.z); a[7] = (short)f2bf(f1.w);
#pragma unroll
            for (int c = 0; c < 8; ++c) {
                const int nn = (c << 4) + l16;
                const bfrag b = *(const bfrag*)(Wb + nn * TPITCH + koff);
                acc[c] = __builtin_amdgcn_mfma_f32_16x16x32_bf16(a, b, acc[c], 0, 0, 0);
            }
        }

#pragma unroll
        for (int r = 0; r < 4; ++r) {
            const int row = r0 + (quad << 2) + r;
            if (row < n) {
                u16* orow = Tb + (size_t)row * DIM + l16;
#pragma unroll
                for (int c = 0; c < 8; ++c)
                    orow[c << 4] = f2bf(acc[c][r]);
            }
        }
    }
}

// ---------------------------------------------------------------------------
// K2: single-block exclusive scan of tot[NBK] -> bucketStart[NBK+1], cursor
// ---------------------------------------------------------------------------
__global__ __launch_bounds__(256) void k_scan(
    const int* __restrict__ tot, int* __restrict__ bucketStart,
    int* __restrict__ cursor, int NBK, int E)
{
    __shared__ int sc[256];
    __shared__ int carry_s;
    const int t = threadIdx.x;
    if (t == 0) carry_s = 0;
    __syncthreads();
    for (int base = 0; base < NBK; base += 256) {
        const int idx = base + t;
        const int v = (idx < NBK) ? tot[idx] : 0;
        sc[t] = v; __syncthreads();
        for (int d = 1; d < 256; d <<= 1) {
            int u = (t >= d) ? sc[t - d] : 0;
            __syncthreads();
            sc[t] += u;
            __syncthreads();
        }
        const int ex = carry_s + sc[t] - v;
        if (idx < NBK) { bucketStart[idx] = ex; cursor[idx] = ex; }
        __syncthreads();
        if (t == 255) carry_s += sc[255];
        __syncthreads();
    }
    if (t == 0) bucketStart[NBK] = E;
}

// ---------------------------------------------------------------------------
// K3: scatter with run reservation. Count chunk in LDS, reserve a contiguous
// run per touched bucket via one global atomicAdd, then scatter into the run.
// Payload: x = src | (dst & 255) << 20, y = w bits.
// ---------------------------------------------------------------------------
__global__ __launch_bounds__(256) void k_scatter(
    const int* __restrict__ src, const int* __restrict__ dst,
    const float* __restrict__ w, int* __restrict__ cursor,
    int2* __restrict__ es1, int E, int NBK)
{
    __shared__ int lh[NBK_MAX];
    const int t = threadIdx.x;
    for (int b = t; b < NBK; b += 256) lh[b] = 0;
    __syncthreads();

    const int base = blockIdx.x * CHUNK;
    const int end  = min(base + CHUNK, E);
    for (int i = base + t; i < end; i += 256)
        atomicAdd(&lh[dst[i] >> BSH], 1);
    __syncthreads();

    for (int b = t; b < NBK; b += 256) {
        const int c = lh[b];
        lh[b] = c ? atomicAdd(&cursor[b], c) : 0;
    }
    __syncthreads();

    for (int i = base + t; i < end; i += 256) {
        const int d = dst[i];
        const int p = atomicAdd(&lh[d >> BSH], 1);
        es1[p] = make_int2(src[i] | ((d & (BSIZE - 1)) << 20),
                           __float_as_int(w[i]));
    }
}

// ---------------------------------------------------------------------------
// K4: fine sort within a bucket (256 nodes, ~4096 edges, block-exclusive):
// exact CSR off[] + final es2 (dlocal stripped).
// ---------------------------------------------------------------------------
__global__ __launch_bounds__(256) void k_fine(
    const int2* __restrict__ es1, const int* __restrict__ bucketStart,
    int2* __restrict__ es2, int* __restrict__ off, int n, int NBK, int E)
{
    __shared__ int cfine[BSIZE];
    __shared__ int cur[BSIZE];
    __shared__ int sums[256];

    const int b = blockIdx.x;
    const int s = bucketStart[b], e = bucketStart[b + 1];
    const int t = threadIdx.x;

    cfine[t] = 0;
    __syncthreads();
    for (int i = s + t; i < e; i += 256)
        atomicAdd(&cfine[es1[i].x >> 20], 1);
    __syncthreads();

    const int c = cfine[t];
    sums[t] = c; __syncthreads();
    for (int d = 1; d < 256; d <<= 1) {
        int v = (t >= d) ? sums[t - d] : 0;
        __syncthreads();
        sums[t] += v;
        __syncthreads();
    }
    const int p = s + sums[t] - c;
    cur[t] = p;

    const int v = (b << BSH) + t;
    if (v < n) off[v] = p;
    if (b == NBK - 1 && t == 0) off[n] = E;
    __syncthreads();

    for (int i = s + t; i < e; i += 256) {
        const int2 ev = es1[i];
        const int pp = atomicAdd(&cur[ev.x >> 20], 1);
        es2[pp] = make_int2(ev.x & 0xFFFFF, ev.y);
    }
}

// ---------------------------------------------------------------------------
// K5: aggregate. One wave per node; lane holds 1 dword (2 bf16); unroll-4.
// ---------------------------------------------------------------------------
__global__ __launch_bounds__(256) void gnn_aggregate(
    const u16* __restrict__ Tb, const int* __restrict__ off,
    const int2* __restrict__ es, float* __restrict__ out, int n)
{
    const int v = blockIdx.x * 4 + (threadIdx.x >> 6);
    if (v >= n) return;
    const int lane = threadIdx.x & 63;
    const u32* Tw = (const u32*)Tb;

    const int b = off[v], e = off[v + 1];
    float ax = 0.f, ay = 0.f;

    int i = b;
    for (; i + 3 < e; i += 4) {
        const int2 e0 = es[i], e1 = es[i + 1], e2 = es[i + 2], e3 = es[i + 3];
        const u32 t0 = Tw[(size_t)e0.x * 64 + lane];
        const u32 t1 = Tw[(size_t)e1.x * 64 + lane];
        const u32 t2 = Tw[(size_t)e2.x * 64 + lane];
        const u32 t3 = Tw[(size_t)e3.x * 64 + lane];
        const float w0 = __int_as_float(e0.y), w1 = __int_as_float(e1.y);
        const float w2 = __int_as_float(e2.y), w3 = __int_as_float(e3.y);
        ax += w0 * __uint_as_float(t0 << 16);
        ay += w0 * __uint_as_float(t0 & 0xFFFF0000u);
        ax += w1 * __uint_as_float(t1 << 16);
        ay += w1 * __uint_as_float(t1 & 0xFFFF0000u);
        ax += w2 * __uint_as_float(t2 << 16);
        ay += w2 * __uint_as_float(t2 & 0xFFFF0000u);
        ax += w3 * __uint_as_float(t3 << 16);
        ay += w3 * __uint_as_float(t3 & 0xFFFF0000u);
    }
    for (; i < e; ++i) {
        const int2 ev = es[i];
        const u32 t = Tw[(size_t)ev.x * 64 + lane];
        const float w = __int_as_float(ev.y);
        ax += w * __uint_as_float(t << 16);
        ay += w * __uint_as_float(t & 0xFFFF0000u);
    }

    *(float2*)(out + (size_t)v * DIM + 2 * lane) = make_float2(ax, ay);
}

// ---------------------------------------------------------------------------
extern "C" void kernel_launch(void* const* d_in, const int* in_sizes, int n_in,
                              void* d_out, int out_size, void* d_ws, size_t ws_size,
                              hipStream_t stream)
{
    const float* node_emb = (const float*)d_in[0];
    const float* ew       = (const float*)d_in[1];
    const int*   srcp     = (const int*)d_in[2];
    const int*   dstp     = (const int*)d_in[3];
    const float* W        = (const float*)d_in[4];
    float* out = (float*)d_out;

    const int n = in_sizes[0] / DIM;            // 100000
    const int E = in_sizes[1];                  // 1600000
    const int NBK  = (n + BSIZE - 1) >> BSH;    // 391 fine buckets
    const int nCnt = (E + CHUNK - 1) / CHUNK;   // 782 chunks

    // workspace layout (256B-aligned chunks)
    char* ws = (char*)d_ws;
    size_t o = 0;
    u16* Tb = (u16*)(ws + o);  o += (((size_t)n * DIM * sizeof(u16)) + 255) & ~255ULL;
    int* tot = (int*)(ws + o); o += (((size_t)NBK * sizeof(int)) + 255) & ~255ULL;
    size_t totBytes = ((size_t)NBK * sizeof(int) + 255) & ~255ULL;
    int* bucketStart = (int*)(ws + o); o += (((size_t)(NBK + 1) * sizeof(int)) + 255) & ~255ULL;
    int* cursor = (int*)(ws + o); o += (((size_t)NBK * sizeof(int)) + 255) & ~255ULL;
    int* off = (int*)(ws + o); o += (((size_t)(n + 1) * sizeof(int)) + 255) & ~255ULL;
    int2* es1 = (int2*)(ws + o); o += (((size_t)E * sizeof(int2)) + 255) & ~255ULL;
    int2* es2 = (int2*)(ws + o);

    // zero the global histogram
    (void)hipMemsetAsync(tot, 0, totBytes, stream);

    // K1: fused chunk-histogram + MFMA transform
    const int nTile = (n + 255) >> 8;
    k_count_transform<<<nCnt + nTile, 256, 0, stream>>>(
        node_emb, W, Tb, dstp, tot, n, E, nCnt, NBK);

    // K2: scan bucket totals -> bucketStart + cursor
    k_scan<<<1, 256, 0, stream>>>(tot, bucketStart, cursor, NBK, E);

    // K3: reservation scatter into bucket runs
    k_scatter<<<nCnt, 256, 0, stream>>>(srcp, dstp, ew, cursor, es1, E, NBK);

    // K4: fine sort within buckets -> exact CSR (off, es2)
    k_fine<<<NBK, 256, 0, stream>>>(es1, bucketStart, es2, off, n, NBK, E);

    // K5: aggregate (one wave per node)
    gnn_aggregate<<<(n + 3) / 4, 256, 0, stream>>>(Tb, off, es2, out, n);
}